// Round 5
// baseline (252.922 us; speedup 1.0000x reference)
//
#include <hip/hip_runtime.h>

#define NROWS   262144
#define DCOLS   128
#define NBLOCKS 2048
#define MARGIN_SQ 0.390625f   // (1.25/2)^2

typedef float v4f __attribute__((ext_vector_type(4)));

// Layout: 8 lanes per row (lane = rg*8 + c). A wave covers 4 groups x 8 rows
// = 32 contiguous rows, software-pipelined: group g+1's 8 dwordx4 nt-loads
// are issued BEFORE group g is consumed (double-buffered), so the wave keeps
// ~8-16 loads in flight through the whole loop instead of draining per
// iteration. Desire loads hoisted to the prologue.
__global__ __launch_bounds__(256) void fra_main(const float* __restrict__ o1,
                                                const float* __restrict__ o2,
                                                const float* __restrict__ desire,
                                                float* __restrict__ ws) {
    __shared__ float s_inter[4], s_act[4], s_des[4];
    const int tid  = threadIdx.x;
    const int lane = tid & 63;
    const int wave = tid >> 6;          // 0..3
    const int c    = lane & 7;          // 16B chunk column (0..7)
    const int rg   = lane >> 3;         // row within group (0..7)
    const int gw   = blockIdx.x * 4 + wave;   // 0..8191

    // Base element offset for this lane's (group 0) loads.
    const int row0 = gw * 32 + rg;                    // first row this lane touches
    const size_t base = (size_t)row0 * DCOLS + c * 4; // float index, 16B aligned
    const v4f* __restrict__ pa = (const v4f*)(o1 + base);
    const v4f* __restrict__ pb = (const v4f*)(o2 + base);
    // v4f-unit strides: group = 8 rows * 128 fl / 4 = 256; chunk k = 32 fl / 4 = 8.

    // Hoist the 4 desire loads (oldest in the vmcnt queue).
    float des[4];
    #pragma unroll
    for (int g = 0; g < 4; g++) des[g] = desire[row0 + g * 8];

    v4f va[2][4], vb[2][4];

    #define LOAD_GROUP(g, s)                                                  \
        _Pragma("unroll") for (int k = 0; k < 4; k++) {                       \
            va[s][k] = __builtin_nontemporal_load(&pa[(g) * 256 + k * 8]);    \
            vb[s][k] = __builtin_nontemporal_load(&pb[(g) * 256 + k * 8]);    \
        }

    LOAD_GROUP(0, 0);

    float l_inter = 0.0f, l_act = 0.0f, l_des = 0.0f;

    #pragma unroll
    for (int g = 0; g < 4; g++) {
        const int s  = g & 1;
        const int ns = s ^ 1;
        if (g == 0) { LOAD_GROUP(1, 1); }
        else if (g == 1) { LOAD_GROUP(2, 0); }
        else if (g == 2) { LOAD_GROUP(3, 1); }

        float acc = 0.0f;
        #pragma unroll
        for (int k = 0; k < 4; k++) {
            const v4f d = va[s][k] - vb[s][k];
            acc += d.x * d.x + d.y * d.y + d.z * d.z + d.w * d.w;
        }
        (void)ns;

        // Row sum across the 8 c-lanes (DPP-friendly small xors).
        acc += __shfl_xor(acc, 1);
        acc += __shfl_xor(acc, 2);
        acc += __shfl_xor(acc, 4);

        const float act = (acc > MARGIN_SQ) ? 1.0f : 0.0f;
        const float d   = des[g];
        l_act   += act;
        l_des   += d;
        l_inter += act * d;
    }
    #undef LOAD_GROUP

    // All 8 c-lanes of an rg hold identical l_*; reduce across rg only
    // (xor 8,16,32) -> every lane ends with the exact 32-row sum, no scaling.
    l_inter += __shfl_xor(l_inter, 8);
    l_act   += __shfl_xor(l_act,   8);
    l_des   += __shfl_xor(l_des,   8);
    l_inter += __shfl_xor(l_inter, 16);
    l_act   += __shfl_xor(l_act,   16);
    l_des   += __shfl_xor(l_des,   16);
    l_inter += __shfl_xor(l_inter, 32);
    l_act   += __shfl_xor(l_act,   32);
    l_des   += __shfl_xor(l_des,   32);

    if (lane == 0) {
        s_inter[wave] = l_inter;
        s_act[wave]   = l_act;
        s_des[wave]   = l_des;
    }
    __syncthreads();
    if (tid == 0) {
        ws[blockIdx.x]               = s_inter[0] + s_inter[1] + s_inter[2] + s_inter[3];
        ws[NBLOCKS + blockIdx.x]     = s_act[0]   + s_act[1]   + s_act[2]   + s_act[3];
        ws[2 * NBLOCKS + blockIdx.x] = s_des[0]   + s_des[1]   + s_des[2]   + s_des[3];
    }
}

__global__ __launch_bounds__(1024) void fra_reduce(const float* __restrict__ ws,
                                                   float* __restrict__ out) {
    __shared__ float s[3][16];
    const int t = threadIdx.x;
    float i = ws[t]        + ws[t + 1024];
    float a = ws[2048 + t] + ws[2048 + t + 1024];
    float d = ws[4096 + t] + ws[4096 + t + 1024];

    #pragma unroll
    for (int off = 32; off >= 1; off >>= 1) {
        i += __shfl_xor(i, off);
        a += __shfl_xor(a, off);
        d += __shfl_xor(d, off);
    }
    const int lane = t & 63, w = t >> 6;
    if (lane == 0) { s[0][w] = i; s[1][w] = a; s[2][w] = d; }
    __syncthreads();
    if (t == 0) {
        float ti = 0.0f, ta = 0.0f, td = 0.0f;
        #pragma unroll
        for (int k = 0; k < 16; k++) { ti += s[0][k]; ta += s[1][k]; td += s[2][k]; }
        const float uni = ta + td - ti;
        out[0] = (ti + 1e-6f) / (uni + 1e-6f);
    }
}

extern "C" void kernel_launch(void* const* d_in, const int* in_sizes, int n_in,
                              void* d_out, int out_size, void* d_ws, size_t ws_size,
                              hipStream_t stream) {
    const float* o1     = (const float*)d_in[0];
    const float* o2     = (const float*)d_in[1];
    const float* desire = (const float*)d_in[2];
    float*       out    = (float*)d_out;
    float*       ws     = (float*)d_ws;

    fra_main<<<NBLOCKS, 256, 0, stream>>>(o1, o2, desire, ws);
    fra_reduce<<<1, 1024, 0, stream>>>(ws, out);
}